// Round 2
// baseline (3113.909 us; speedup 1.0000x reference)
//
#include <hip/hip_runtime.h>
#include <float.h>
#include <math.h>

typedef __attribute__((ext_vector_type(8))) short bf16x8;
typedef __attribute__((ext_vector_type(4))) float f32x4;

// d_out float offsets (loss, quantized, perplexity, embedding, indices, encodings)
#define O_Q    1
#define O_PERP 8388609
#define O_EMB  8388610
#define O_IDX  9437186
#define O_ENC  9469954

// workspace float offsets: ETpk limb-image at 0 (4 MB)
#define W_CB   1048576
#define W_CNT  1052672
#define W_BS   1056768

#define MARGIN 0.01f

__device__ __forceinline__ unsigned short bf16_rne(float x) {
    unsigned u = __float_as_uint(x);
    unsigned r = u + 0x7FFFu + ((u >> 16) & 1u);
    return (unsigned short)(r >> 16);
}

__device__ __forceinline__ void gld_lds16(const void* g, void* l) {
    __builtin_amdgcn_global_load_lds(
        (const __attribute__((address_space(1))) unsigned int*)g,
        (__attribute__((address_space(3))) unsigned int*)l, 16, 0, 0);
}

__device__ __forceinline__ unsigned long long u64min(unsigned long long a, unsigned long long b){ return a < b ? a : b; }
__device__ __forceinline__ unsigned long long u64max(unsigned long long a, unsigned long long b){ return a > b ? a : b; }

__device__ __forceinline__ unsigned long long packkey(float s, int k) {
    unsigned u = __float_as_uint(s);
    u = (u & 0x80000000u) ? ~u : (u | 0x80000000u);
    return ((unsigned long long)u << 32) | (unsigned)k;
}
__device__ __forceinline__ float unpackf(unsigned long long key) {
    unsigned u = (unsigned)(key >> 32);
    u = (u & 0x80000000u) ? (u & 0x7FFFFFFFu) : ~u;
    return __uint_as_float(u);
}

// ---- E -> limb image for global_load_lds staging.
// chunk(kt,dt) 32KB = [limb2][codefrag16][64 units x 16B], unit=(c*16+row)
__global__ __launch_bounds__(256)
void k_prep(const float* __restrict__ E, char* __restrict__ ETpk)
{
    int gid = blockIdx.x * 256 + threadIdx.x;   // 131072 = 4096 codes * 32 octets
    int code = gid >> 5, oct = gid & 31;
    const float* ep = E + (size_t)code * 256 + oct * 8;
    float4 a = *(const float4*)ep, c4 = *(const float4*)(ep + 4);
    float v[8] = {a.x, a.y, a.z, a.w, c4.x, c4.y, c4.z, c4.w};
    unsigned hw[8], lw[8];
#pragma unroll
    for (int i = 0; i < 8; ++i) {
        unsigned short h = bf16_rne(v[i]);
        float hf = __uint_as_float((unsigned)h << 16);
        hw[i] = h; lw[i] = bf16_rne(v[i] - hf);
    }
    uint4 vh = {hw[0]|(hw[1]<<16), hw[2]|(hw[3]<<16), hw[4]|(hw[5]<<16), hw[6]|(hw[7]<<16)};
    uint4 vl = {lw[0]|(lw[1]<<16), lw[2]|(lw[3]<<16), lw[4]|(lw[5]<<16), lw[6]|(lw[7]<<16)};
    int kt = code >> 8, cf = (code >> 4) & 15, row = code & 15;
    int dtv = oct >> 2, c = oct & 3;
    size_t chunk = (size_t)(kt * 8 + dtv) * 32768;
    *(uint4*)(ETpk + chunk + (size_t)((0*16 + cf) * 64 + (c*16 + row)) * 16) = vh;
    *(uint4*)(ETpk + chunk + (size_t)((1*16 + cf) * 64 + (c*16 + row)) * 16) = vl;
}

// ---- 0.5*||e_k||^2 (fp32)
__global__ __launch_bounds__(256)
void k_cbias(const float* __restrict__ E, float* __restrict__ cb)
{
    const int tid = threadIdx.x;
    const int k   = blockIdx.x * 16 + (tid >> 4);
    const int ch  = tid & 15;
    const float* p = E + (size_t)k * 256 + ch * 16;
    float s = 0.f;
#pragma unroll
    for (int i = 0; i < 4; ++i) {
        float4 v = *(const float4*)(p + i * 4);
        s += v.x*v.x + v.y*v.y + v.z*v.z + v.w*v.w;
    }
#pragma unroll
    for (int m = 1; m < 16; m <<= 1) s += __shfl_xor(s, m, 64);
    if (ch == 0) cb[k] = 0.5f * s;
}

// ---- main: limb-MFMA distances + top2 argmin + rescore + fused outputs
// grid 256, block 512 (8 waves 2Mx4N), tile 128 tok x 256 codes/kt, dk=32 dbuf
__global__ __launch_bounds__(512, 2)
void k_main(const float* __restrict__ X, const char* __restrict__ ETpk,
            const float* __restrict__ cbh, const float* __restrict__ E,
            float* __restrict__ out, int* __restrict__ counts,
            float* __restrict__ bscore)
{
    extern __shared__ char lds[];   // A: [buf][0,16K) at 0/16384 ; B: [buf][32K) at 32768/65536

    const int tid  = threadIdx.x;
    const int lane = tid & 63;
    const int wid  = tid >> 6;
    const int wm   = wid >> 2;      // 0..1 token half
    const int wn   = wid & 3;       // 0..3 code quarter
    const int n0   = blockIdx.x * 128;
    const int b    = n0 >> 10;
    const int l0   = n0 & 1023;
    const int tokA = tid & 127;     // A-staging unit: (token, d-octet)
    const int octA = tid >> 7;

    f32x4 acc[4][4];
#pragma unroll
    for (int mi = 0; mi < 4; ++mi)
#pragma unroll
        for (int nj = 0; nj < 4; ++nj) acc[mi][nj] = (f32x4){0.f,0.f,0.f,0.f};

    float s1[16], s2[16];
    int   i1[16], i2[16];
#pragma unroll
    for (int s = 0; s < 16; ++s) { s1[s] = FLT_MAX; s2[s] = FLT_MAX; i1[s] = 0; i2[s] = 0; }

    const size_t xbase = (size_t)b * 262144 + l0;

    auto stageB = [&](int rnd, int bufsel) {
        const char* src = ETpk + (size_t)rnd * 32768;
        char* dst = lds + 32768 + bufsel * 32768;
#pragma unroll
        for (int i = 0; i < 4; ++i)
            gld_lds16(src + i*8192 + tid*16, dst + i*8192 + tid*16);
    };
    auto loadA = [&](int rnd, float* xa) {
        const float* src = X + xbase + (size_t)((rnd & 7) * 32 + octA * 8) * 1024 + tokA;
#pragma unroll
        for (int i = 0; i < 8; ++i) xa[i] = src[(size_t)i * 1024];
    };
    auto writeA = [&](int bufsel, const float* xa) {
        unsigned hw[8], lw[8];
#pragma unroll
        for (int i = 0; i < 8; ++i) {
            unsigned short h16 = bf16_rne(xa[i]);
            float hf = __uint_as_float((unsigned)h16 << 16);
            hw[i] = h16; lw[i] = bf16_rne(xa[i] - hf);
        }
        uint4 vh = {hw[0]|(hw[1]<<16), hw[2]|(hw[3]<<16), hw[4]|(hw[5]<<16), hw[6]|(hw[7]<<16)};
        uint4 vl = {lw[0]|(lw[1]<<16), lw[2]|(lw[3]<<16), lw[4]|(lw[5]<<16), lw[6]|(lw[7]<<16)};
        char* dstc = lds + bufsel * 16384 + (tokA >> 4) * 1024 + (octA * 16 + (tokA & 15)) * 16;
        *(uint4*)dstc = vh;
        *(uint4*)(dstc + 8192) = vl;
    };

    // prologue: stage round 0
    {
        float xa[8];
        stageB(0, 0);
        loadA(0, xa);
        writeA(0, xa);
    }
    __syncthreads();

#pragma unroll 1
    for (int rd = 0; rd < 128; ++rd) {
        const int bsel = rd & 1;
        const int nxt = rd + 1;
        float xa[8];
        if (nxt < 128) { stageB(nxt, nxt & 1); loadA(nxt, xa); }

        // compute one k32-step
        {
            const char* A  = lds + bsel * 16384;
            const char* Bp = lds + 32768 + bsel * 32768;
            bf16x8 af[2][4];
#pragma unroll
            for (int limb = 0; limb < 2; ++limb)
#pragma unroll
                for (int mi = 0; mi < 4; ++mi)
                    af[limb][mi] = *(const bf16x8*)(A + limb*8192 + (wm*4 + mi)*1024 + lane*16);
#pragma unroll
            for (int nj = 0; nj < 4; ++nj) {
                bf16x8 b0 = *(const bf16x8*)(Bp + (wn*4 + nj)*1024 + lane*16);
                bf16x8 b1 = *(const bf16x8*)(Bp + 16384 + (wn*4 + nj)*1024 + lane*16);
#pragma unroll
                for (int mi = 0; mi < 4; ++mi) {
                    acc[mi][nj] = __builtin_amdgcn_mfma_f32_16x16x32_bf16(af[0][mi], b0, acc[mi][nj], 0, 0, 0);
                    acc[mi][nj] = __builtin_amdgcn_mfma_f32_16x16x32_bf16(af[0][mi], b1, acc[mi][nj], 0, 0, 0);
                    acc[mi][nj] = __builtin_amdgcn_mfma_f32_16x16x32_bf16(af[1][mi], b0, acc[mi][nj], 0, 0, 0);
                    acc[mi][nj] = __builtin_amdgcn_mfma_f32_16x16x32_bf16(af[1][mi], b1, acc[mi][nj], 0, 0, 0);
                }
            }
        }

        if ((rd & 7) == 7) {
            const int kt = rd >> 3;
            // score = 0.5||e||^2 - x.e ; top2 update (scan order = k ascending per lane)
            const int cb0 = kt * 256 + wn * 64 + (lane & 15);
            float cbv[4];
#pragma unroll
            for (int nj = 0; nj < 4; ++nj) cbv[nj] = cbh[cb0 + nj * 16];
#pragma unroll
            for (int mi = 0; mi < 4; ++mi)
#pragma unroll
                for (int q = 0; q < 4; ++q) {
                    const int slot = mi * 4 + q;
#pragma unroll
                    for (int nj = 0; nj < 4; ++nj) {
                        float s = cbv[nj] - acc[mi][nj][q];
                        int code = cb0 + nj * 16;
                        bool c1 = s < s1[slot];
                        bool c2 = s < s2[slot];
                        if (c1) { s2[slot] = s1[slot]; i2[slot] = i1[slot]; s1[slot] = s; i1[slot] = code; }
                        else if (c2) { s2[slot] = s; i2[slot] = code; }
                        acc[mi][nj][q] = 0.f;
                    }
                }
            // interleaved one-hot zero-fill for this kt chunk (128 tok x 256 codes)
            float2 z2 = make_float2(0.f, 0.f);
#pragma unroll 4
            for (int i = 0; i < 32; ++i) {
                int lin = i * 512 + tid;
                int t = lin >> 7, c2i = lin & 127;
                *(float2*)(out + (size_t)O_ENC + (size_t)(n0 + t) * 4096 + kt * 256 + c2i * 2) = z2;
            }
        }

        if (nxt < 128) writeA(nxt & 1, xa);
        __syncthreads();
    }

    // pack keys and butterfly-merge top2 across the 16 code-lanes
    unsigned long long key1[16], key2[16];
#pragma unroll
    for (int s = 0; s < 16; ++s) { key1[s] = packkey(s1[s], i1[s]); key2[s] = packkey(s2[s], i2[s]); }
#pragma unroll
    for (int m = 1; m < 16; m <<= 1) {
#pragma unroll
        for (int s = 0; s < 16; ++s) {
            unsigned long long o1 = __shfl_xor(key1[s], m, 64);
            unsigned long long o2 = __shfl_xor(key2[s], m, 64);
            unsigned long long lo = u64min(key1[s], o1);
            unsigned long long hi = u64min(u64max(key1[s], o1), u64min(key2[s], o2));
            key1[s] = lo; key2[s] = hi;
        }
    }

    // write per-(token, wave-col) top2 pairs to LDS scratch, merge, rescore
    unsigned long long* scr = (unsigned long long*)lds;       // 128*4*2 u64 = 8 KB
    int* ids = (int*)(lds + 16384);                           // 128 ints
    float* wp = (float*)(lds + 16384 + 512);                  // 8 floats
    if ((lane & 15) == 0) {
#pragma unroll
        for (int mi = 0; mi < 4; ++mi)
#pragma unroll
            for (int q = 0; q < 4; ++q) {
                int slot = mi * 4 + q;
                int tl = wm * 64 + mi * 16 + ((lane >> 4) << 2) + q;
                scr[(tl * 4 + wn) * 2    ] = key1[slot];
                scr[(tl * 4 + wn) * 2 + 1] = key2[slot];
            }
    }
    __syncthreads();

    if (tid < 128) {
        unsigned long long a1 = scr[tid * 8], a2 = scr[tid * 8 + 1];
#pragma unroll
        for (int w = 1; w < 4; ++w) {
            unsigned long long b1 = scr[(tid * 4 + w) * 2];
            unsigned long long b2 = scr[(tid * 4 + w) * 2 + 1];
            unsigned long long lo = u64min(a1, b1);
            unsigned long long hi = u64min(u64max(a1, b1), u64min(a2, b2));
            a1 = lo; a2 = hi;
        }
        int k = (int)(a1 & 0xFFFFFFFFull);
        float g1 = unpackf(a1), g2 = unpackf(a2);
        if (g2 - g1 <= MARGIN) {
            // exact fp32 rescore of both candidates
            int ka = k, kb = (int)(a2 & 0xFFFFFFFFull);
            float d1 = 0.f, d2 = 0.f;
            for (int d = 0; d < 256; ++d) {
                float xv = X[xbase + (size_t)d * 1024 + tid];
                float e1 = E[(size_t)ka * 256 + d];
                float e2 = E[(size_t)kb * 256 + d];
                float f1 = xv - e1, f2 = xv - e2;
                d1 += f1 * f1; d2 += f2 * f2;
            }
            if (d2 < d1 || (d2 == d1 && kb < ka)) k = kb;
        }
        ids[tid] = k;
        out[(size_t)O_IDX + n0 + tid] = (float)k;
        atomicAdd(&counts[k], 1);
        out[(size_t)O_ENC + (size_t)(n0 + tid) * 4096 + k] = 1.0f;
    }
    __syncthreads();

    // fused quantize (STE arithmetic) + exact fp32 loss partial
    float dl = 0.f;
#pragma unroll 4
    for (int r = 0; r < 64; ++r) {
        int lin = r * 512 + tid;
        int d = lin >> 7, t = lin & 127;
        float q  = E[(size_t)ids[t] * 256 + d];
        float xv = X[xbase + (size_t)d * 1024 + t];
        out[(size_t)O_Q + xbase + (size_t)d * 1024 + t] = xv + (q - xv);
        float df = q - xv;
        dl += df * df;
    }
#pragma unroll
    for (int m = 1; m < 64; m <<= 1) dl += __shfl_xor(dl, m, 64);
    if (lane == 0) wp[wid] = dl;
    __syncthreads();
    if (tid == 0) {
        float s = 0.f;
#pragma unroll
        for (int w = 0; w < 8; ++w) s += wp[w];
        bscore[blockIdx.x] = s;
    }
}

// ---- scalars: loss + perplexity
__global__ __launch_bounds__(256)
void k_final(const float* __restrict__ bscore, const int* __restrict__ counts,
             float* __restrict__ out)
{
    const int tid = threadIdx.x;
    float s = bscore[tid];
    float h = 0.f;
#pragma unroll
    for (int i = 0; i < 16; ++i) {
        float p = (float)counts[tid * 16 + i] * (1.0f / 32768.f);
        h += p * logf(p + 1e-10f);
    }
#pragma unroll
    for (int m = 1; m < 64; m <<= 1) {
        s += __shfl_xor(s, m, 64);
        h += __shfl_xor(h, m, 64);
    }
    __shared__ float rs[4], rh[4];
    if ((tid & 63) == 0) { rs[tid >> 6] = s; rh[tid >> 6] = h; }
    __syncthreads();
    if (tid == 0) {
        float S = rs[0] + rs[1] + rs[2] + rs[3];
        float H = rh[0] + rh[1] + rh[2] + rh[3];
        out[0]      = 0.25f * S / 8388608.f;
        out[O_PERP] = expf(-H);
    }
}

extern "C" void kernel_launch(void* const* d_in, const int* in_sizes, int n_in,
                              void* d_out, int out_size, void* d_ws, size_t ws_size,
                              hipStream_t stream)
{
    (void)in_sizes; (void)n_in; (void)out_size; (void)ws_size;
    const float* X = (const float*)d_in[0];
    const float* E = (const float*)d_in[1];
    float* out = (float*)d_out;
    float* ws  = (float*)d_ws;
    char*  ETpk   = (char*)ws;
    float* cbh    = ws + W_CB;
    int*   counts = (int*)(ws + W_CNT);
    float* bsc    = ws + W_BS;

    hipMemsetAsync(counts, 0, 4096 * sizeof(int), stream);
    k_prep <<<512, 256, 0, stream>>>(E, ETpk);
    k_cbias<<<256, 256, 0, stream>>>(E, cbh);
    hipFuncSetAttribute((const void*)k_main, hipFuncAttributeMaxDynamicSharedMemorySize, 98304);
    k_main <<<256, 512, 98304, stream>>>(X, ETpk, cbh, E, out, counts, bsc);
    k_final<<<1, 256, 0, stream>>>(bsc, counts, out);
    hipMemcpyAsync(out + O_EMB, E, (size_t)4096 * 256 * sizeof(float),
                   hipMemcpyDeviceToDevice, stream);
}

// Round 3
// 522.980 us; speedup vs baseline: 5.9542x; 5.9542x over previous
//
#include <hip/hip_runtime.h>
#include <float.h>
#include <math.h>

typedef __attribute__((ext_vector_type(8))) short bf16x8;
typedef __attribute__((ext_vector_type(4))) float f32x4;

// d_out float offsets (loss, quantized, perplexity, embedding, indices, encodings)
#define O_Q    1
#define O_PERP 8388609
#define O_EMB  8388610
#define O_IDX  9437186
#define O_ENC  9469954

// workspace float offsets: ETpk limb-image at 0 (4 MB)
#define W_CB   1048576
#define W_CNT  1052672
#define W_BS   1056768

#define MARGIN 0.01f

__device__ __forceinline__ unsigned short bf16_rne(float x) {
    unsigned u = __float_as_uint(x);
    unsigned r = u + 0x7FFFu + ((u >> 16) & 1u);
    return (unsigned short)(r >> 16);
}

__device__ __forceinline__ void gld_lds16(const void* g, void* l) {
    __builtin_amdgcn_global_load_lds(
        (const __attribute__((address_space(1))) unsigned int*)g,
        (__attribute__((address_space(3))) unsigned int*)l, 16, 0, 0);
}

__device__ __forceinline__ unsigned long long u64min(unsigned long long a, unsigned long long b){ return a < b ? a : b; }
__device__ __forceinline__ unsigned long long u64max(unsigned long long a, unsigned long long b){ return a > b ? a : b; }

__device__ __forceinline__ unsigned long long packkey(float s, int k) {
    unsigned u = __float_as_uint(s);
    u = (u & 0x80000000u) ? ~u : (u | 0x80000000u);
    return ((unsigned long long)u << 32) | (unsigned)k;
}
__device__ __forceinline__ float unpackf(unsigned long long key) {
    unsigned u = (unsigned)(key >> 32);
    u = (u & 0x80000000u) ? (u & 0x7FFFFFFFu) : ~u;
    return __uint_as_float(u);
}

// ---- E -> limb image for global_load_lds staging.
// chunk(kt,dt) 32KB = [limb2][codefrag16][64 units x 16B], unit=(c*16+row)
__global__ __launch_bounds__(256)
void k_prep(const float* __restrict__ E, char* __restrict__ ETpk)
{
    int gid = blockIdx.x * 256 + threadIdx.x;   // 131072 = 4096 codes * 32 octets
    int code = gid >> 5, oct = gid & 31;
    const float* ep = E + (size_t)code * 256 + oct * 8;
    float4 a = *(const float4*)ep, c4 = *(const float4*)(ep + 4);
    float v[8] = {a.x, a.y, a.z, a.w, c4.x, c4.y, c4.z, c4.w};
    unsigned hw[8], lw[8];
#pragma unroll
    for (int i = 0; i < 8; ++i) {
        unsigned short h = bf16_rne(v[i]);
        float hf = __uint_as_float((unsigned)h << 16);
        hw[i] = h; lw[i] = bf16_rne(v[i] - hf);
    }
    uint4 vh = {hw[0]|(hw[1]<<16), hw[2]|(hw[3]<<16), hw[4]|(hw[5]<<16), hw[6]|(hw[7]<<16)};
    uint4 vl = {lw[0]|(lw[1]<<16), lw[2]|(lw[3]<<16), lw[4]|(lw[5]<<16), lw[6]|(lw[7]<<16)};
    int kt = code >> 8, cf = (code >> 4) & 15, row = code & 15;
    int dtv = oct >> 2, c = oct & 3;
    size_t chunk = (size_t)(kt * 8 + dtv) * 32768;
    *(uint4*)(ETpk + chunk + (size_t)((0*16 + cf) * 64 + (c*16 + row)) * 16) = vh;
    *(uint4*)(ETpk + chunk + (size_t)((1*16 + cf) * 64 + (c*16 + row)) * 16) = vl;
}

// ---- 0.5*||e_k||^2 (fp32)
__global__ __launch_bounds__(256)
void k_cbias(const float* __restrict__ E, float* __restrict__ cb)
{
    const int tid = threadIdx.x;
    const int k   = blockIdx.x * 16 + (tid >> 4);
    const int ch  = tid & 15;
    const float* p = E + (size_t)k * 256 + ch * 16;
    float s = 0.f;
#pragma unroll
    for (int i = 0; i < 4; ++i) {
        float4 v = *(const float4*)(p + i * 4);
        s += v.x*v.x + v.y*v.y + v.z*v.z + v.w*v.w;
    }
#pragma unroll
    for (int m = 1; m < 16; m <<= 1) s += __shfl_xor(s, m, 64);
    if (ch == 0) cb[k] = 0.5f * s;
}

// ---- main: limb-MFMA distances + top2 argmin + rescore + fused outputs
// grid 256, block 512 (8 waves 2Mx4N), tile 128 tok x 256 codes/kt, dk=32 dbuf
// VGPR budget: acc 64 + top2 state 48 + phased operands <=96 + misc ~25 -> no spill @256 cap
__global__ __launch_bounds__(512, 1)
void k_main(const float* __restrict__ X, const char* __restrict__ ETpk,
            const float* __restrict__ cbh, const float* __restrict__ E,
            float* __restrict__ out, int* __restrict__ counts,
            float* __restrict__ bscore)
{
    extern __shared__ char lds[];   // A dbuf [0,32K) ; B dbuf [32K,96K)

    const int tid  = threadIdx.x;
    const int lane = tid & 63;
    const int wid  = tid >> 6;
    const int wm   = wid >> 2;      // 0..1 token half
    const int wn   = wid & 3;       // 0..3 code quarter
    const int n0   = blockIdx.x * 128;
    const int b    = n0 >> 10;
    const int l0   = n0 & 1023;
    const int tokA = tid & 127;     // A-staging unit: (token, d-octet)
    const int octA = tid >> 7;

    f32x4 acc[4][4];
#pragma unroll
    for (int mi = 0; mi < 4; ++mi)
#pragma unroll
        for (int nj = 0; nj < 4; ++nj) acc[mi][nj] = (f32x4){0.f,0.f,0.f,0.f};

    // per-slot top2: exact fp32 scores + packed 12-bit codes (i1 = low16, i2 = high16)
    float s1[16], s2[16];
    unsigned ipack[16];
#pragma unroll
    for (int s = 0; s < 16; ++s) { s1[s] = FLT_MAX; s2[s] = FLT_MAX; ipack[s] = 0; }

    const size_t xbase = (size_t)b * 262144 + l0;

    auto stageB = [&](int rnd, int bufsel) {
        const char* src = ETpk + (size_t)rnd * 32768;
        char* dst = lds + 32768 + bufsel * 32768;
#pragma unroll
        for (int i = 0; i < 4; ++i)
            gld_lds16(src + i*8192 + tid*16, dst + i*8192 + tid*16);
    };
    auto loadA = [&](int rnd, float* xa) {
        const float* src = X + xbase + (size_t)((rnd & 7) * 32 + octA * 8) * 1024 + tokA;
#pragma unroll
        for (int i = 0; i < 8; ++i) xa[i] = src[(size_t)i * 1024];
    };
    auto writeA = [&](int bufsel, const float* xa) {
        unsigned hw[8], lw[8];
#pragma unroll
        for (int i = 0; i < 8; ++i) {
            unsigned short h16 = bf16_rne(xa[i]);
            float hf = __uint_as_float((unsigned)h16 << 16);
            hw[i] = h16; lw[i] = bf16_rne(xa[i] - hf);
        }
        uint4 vh = {hw[0]|(hw[1]<<16), hw[2]|(hw[3]<<16), hw[4]|(hw[5]<<16), hw[6]|(hw[7]<<16)};
        uint4 vl = {lw[0]|(lw[1]<<16), lw[2]|(lw[3]<<16), lw[4]|(lw[5]<<16), lw[6]|(lw[7]<<16)};
        char* dstc = lds + bufsel * 16384 + (tokA >> 4) * 1024 + (octA * 16 + (tokA & 15)) * 16;
        *(uint4*)dstc = vh;
        *(uint4*)(dstc + 8192) = vl;
    };

    // prologue: stage round 0
    {
        float xa[8];
        stageB(0, 0);
        loadA(0, xa);
        writeA(0, xa);
    }
    __syncthreads();

#pragma unroll 1
    for (int rd = 0; rd < 128; ++rd) {
        const int bsel = rd & 1;
        const int nxt = rd + 1;
        float xa[8];
        if (nxt < 128) { stageB(nxt, nxt & 1); loadA(nxt, xa); }

        // one k32-step, phased to cap live operand regs at 12 fragments (96 VGPRs)
        {
            const char* A  = lds + bsel * 16384;
            const char* Bp = lds + 32768 + bsel * 32768;
            bf16x8 ah[4], al[4], bt[4];
            // phase 1: hi*hi
#pragma unroll
            for (int mi = 0; mi < 4; ++mi)
                ah[mi] = *(const bf16x8*)(A + (wm*4 + mi)*1024 + lane*16);
#pragma unroll
            for (int nj = 0; nj < 4; ++nj)
                bt[nj] = *(const bf16x8*)(Bp + (wn*4 + nj)*1024 + lane*16);
#pragma unroll
            for (int nj = 0; nj < 4; ++nj)
#pragma unroll
                for (int mi = 0; mi < 4; ++mi)
                    acc[mi][nj] = __builtin_amdgcn_mfma_f32_16x16x32_bf16(ah[mi], bt[nj], acc[mi][nj], 0, 0, 0);
            // phase 2: lo*hi (bt still = bh)
#pragma unroll
            for (int mi = 0; mi < 4; ++mi)
                al[mi] = *(const bf16x8*)(A + 8192 + (wm*4 + mi)*1024 + lane*16);
#pragma unroll
            for (int nj = 0; nj < 4; ++nj)
#pragma unroll
                for (int mi = 0; mi < 4; ++mi)
                    acc[mi][nj] = __builtin_amdgcn_mfma_f32_16x16x32_bf16(al[mi], bt[nj], acc[mi][nj], 0, 0, 0);
            // phase 3: hi*lo + lo*lo (bt overwritten with bl)
#pragma unroll
            for (int nj = 0; nj < 4; ++nj)
                bt[nj] = *(const bf16x8*)(Bp + 16384 + (wn*4 + nj)*1024 + lane*16);
#pragma unroll
            for (int nj = 0; nj < 4; ++nj)
#pragma unroll
                for (int mi = 0; mi < 4; ++mi) {
                    acc[mi][nj] = __builtin_amdgcn_mfma_f32_16x16x32_bf16(ah[mi], bt[nj], acc[mi][nj], 0, 0, 0);
                    acc[mi][nj] = __builtin_amdgcn_mfma_f32_16x16x32_bf16(al[mi], bt[nj], acc[mi][nj], 0, 0, 0);
                }
        }

        if ((rd & 7) == 7) {
            const int kt = rd >> 3;
            // score = 0.5||e||^2 - x.e ; top2 update (scan order = k ascending per lane)
            const int cb0 = kt * 256 + wn * 64 + (lane & 15);
            float cbv[4];
#pragma unroll
            for (int nj = 0; nj < 4; ++nj) cbv[nj] = cbh[cb0 + nj * 16];
#pragma unroll
            for (int mi = 0; mi < 4; ++mi)
#pragma unroll
                for (int q = 0; q < 4; ++q) {
                    const int slot = mi * 4 + q;
#pragma unroll
                    for (int nj = 0; nj < 4; ++nj) {
                        float s = cbv[nj] - acc[mi][nj][q];
                        unsigned code = (unsigned)(cb0 + nj * 16);
                        if (s < s1[slot]) {
                            s2[slot] = s1[slot];
                            ipack[slot] = ((ipack[slot] & 0xFFFFu) << 16) | code;
                            s1[slot] = s;
                        } else if (s < s2[slot]) {
                            s2[slot] = s;
                            ipack[slot] = (ipack[slot] & 0xFFFFu) | (code << 16);
                        }
                        acc[mi][nj][q] = 0.f;
                    }
                }
            // interleaved one-hot zero-fill for this kt chunk (128 tok x 256 codes)
            float2 z2 = make_float2(0.f, 0.f);
#pragma unroll 4
            for (int i = 0; i < 32; ++i) {
                int lin = i * 512 + tid;
                int t = lin >> 7, c2i = lin & 127;
                *(float2*)(out + (size_t)O_ENC + (size_t)(n0 + t) * 4096 + kt * 256 + c2i * 2) = z2;
            }
        }

        if (nxt < 128) writeA(nxt & 1, xa);
        __syncthreads();
    }

    // pack keys and butterfly-merge top2 across the 16 code-lanes
    unsigned long long key1[16], key2[16];
#pragma unroll
    for (int s = 0; s < 16; ++s) {
        key1[s] = packkey(s1[s], (int)(ipack[s] & 0xFFFFu));
        key2[s] = packkey(s2[s], (int)(ipack[s] >> 16));
    }
#pragma unroll
    for (int m = 1; m < 16; m <<= 1) {
#pragma unroll
        for (int s = 0; s < 16; ++s) {
            unsigned long long o1 = __shfl_xor(key1[s], m, 64);
            unsigned long long o2 = __shfl_xor(key2[s], m, 64);
            unsigned long long lo = u64min(key1[s], o1);
            unsigned long long hi = u64min(u64max(key1[s], o1), u64min(key2[s], o2));
            key1[s] = lo; key2[s] = hi;
        }
    }

    // write per-(token, wave-col) top2 pairs to LDS scratch, merge, rescore
    unsigned long long* scr = (unsigned long long*)lds;       // 128*4*2 u64 = 8 KB
    int* ids = (int*)(lds + 16384);                           // 128 ints
    float* wp = (float*)(lds + 16384 + 512);                  // 8 floats
    if ((lane & 15) == 0) {
#pragma unroll
        for (int mi = 0; mi < 4; ++mi)
#pragma unroll
            for (int q = 0; q < 4; ++q) {
                int slot = mi * 4 + q;
                int tl = wm * 64 + mi * 16 + ((lane >> 4) << 2) + q;
                scr[(tl * 4 + wn) * 2    ] = key1[slot];
                scr[(tl * 4 + wn) * 2 + 1] = key2[slot];
            }
    }
    __syncthreads();

    if (tid < 128) {
        unsigned long long a1 = scr[tid * 8], a2 = scr[tid * 8 + 1];
#pragma unroll
        for (int w = 1; w < 4; ++w) {
            unsigned long long b1 = scr[(tid * 4 + w) * 2];
            unsigned long long b2 = scr[(tid * 4 + w) * 2 + 1];
            unsigned long long lo = u64min(a1, b1);
            unsigned long long hi = u64min(u64max(a1, b1), u64min(a2, b2));
            a1 = lo; a2 = hi;
        }
        int k = (int)(a1 & 0xFFFFFFFFull);
        float g1 = unpackf(a1), g2 = unpackf(a2);
        if (g2 - g1 <= MARGIN) {
            // exact fp32 rescore of both candidates
            int ka = k, kb = (int)(a2 & 0xFFFFFFFFull);
            float d1 = 0.f, d2 = 0.f;
            for (int d = 0; d < 256; d += 2) {
                float xv0 = X[xbase + (size_t)d * 1024 + tid];
                float xv1 = X[xbase + (size_t)(d + 1) * 1024 + tid];
                float e10 = E[(size_t)ka * 256 + d], e11 = E[(size_t)ka * 256 + d + 1];
                float e20 = E[(size_t)kb * 256 + d], e21 = E[(size_t)kb * 256 + d + 1];
                float f10 = xv0 - e10, f11 = xv1 - e11;
                float f20 = xv0 - e20, f21 = xv1 - e21;
                d1 += f10 * f10 + f11 * f11;
                d2 += f20 * f20 + f21 * f21;
            }
            if (d2 < d1 || (d2 == d1 && kb < ka)) k = kb;
        }
        ids[tid] = k;
        out[(size_t)O_IDX + n0 + tid] = (float)k;
        atomicAdd(&counts[k], 1);
        out[(size_t)O_ENC + (size_t)(n0 + tid) * 4096 + k] = 1.0f;
    }
    __syncthreads();

    // fused quantize (STE arithmetic) + exact fp32 loss partial
    float dl = 0.f;
#pragma unroll 4
    for (int r = 0; r < 64; ++r) {
        int lin = r * 512 + tid;
        int d = lin >> 7, t = lin & 127;
        float q  = E[(size_t)ids[t] * 256 + d];
        float xv = X[xbase + (size_t)d * 1024 + t];
        out[(size_t)O_Q + xbase + (size_t)d * 1024 + t] = xv + (q - xv);
        float df = q - xv;
        dl += df * df;
    }
#pragma unroll
    for (int m = 1; m < 64; m <<= 1) dl += __shfl_xor(dl, m, 64);
    if (lane == 0) wp[wid] = dl;
    __syncthreads();
    if (tid == 0) {
        float s = 0.f;
#pragma unroll
        for (int w = 0; w < 8; ++w) s += wp[w];
        bscore[blockIdx.x] = s;
    }
}

// ---- scalars: loss + perplexity
__global__ __launch_bounds__(256)
void k_final(const float* __restrict__ bscore, const int* __restrict__ counts,
             float* __restrict__ out)
{
    const int tid = threadIdx.x;
    float s = bscore[tid];
    float h = 0.f;
#pragma unroll
    for (int i = 0; i < 16; ++i) {
        float p = (float)counts[tid * 16 + i] * (1.0f / 32768.f);
        h += p * logf(p + 1e-10f);
    }
#pragma unroll
    for (int m = 1; m < 64; m <<= 1) {
        s += __shfl_xor(s, m, 64);
        h += __shfl_xor(h, m, 64);
    }
    __shared__ float rs[4], rh[4];
    if ((tid & 63) == 0) { rs[tid >> 6] = s; rh[tid >> 6] = h; }
    __syncthreads();
    if (tid == 0) {
        float S = rs[0] + rs[1] + rs[2] + rs[3];
        float H = rh[0] + rh[1] + rh[2] + rh[3];
        out[0]      = 0.25f * S / 8388608.f;
        out[O_PERP] = expf(-H);
    }
}

extern "C" void kernel_launch(void* const* d_in, const int* in_sizes, int n_in,
                              void* d_out, int out_size, void* d_ws, size_t ws_size,
                              hipStream_t stream)
{
    (void)in_sizes; (void)n_in; (void)out_size; (void)ws_size;
    const float* X = (const float*)d_in[0];
    const float* E = (const float*)d_in[1];
    float* out = (float*)d_out;
    float* ws  = (float*)d_ws;
    char*  ETpk   = (char*)ws;
    float* cbh    = ws + W_CB;
    int*   counts = (int*)(ws + W_CNT);
    float* bsc    = ws + W_BS;

    hipMemsetAsync(counts, 0, 4096 * sizeof(int), stream);
    k_prep <<<512, 256, 0, stream>>>(E, ETpk);
    k_cbias<<<256, 256, 0, stream>>>(E, cbh);
    hipFuncSetAttribute((const void*)k_main, hipFuncAttributeMaxDynamicSharedMemorySize, 98304);
    k_main <<<256, 512, 98304, stream>>>(X, ETpk, cbh, E, out, counts, bsc);
    k_final<<<1, 256, 0, stream>>>(bsc, counts, out);
    hipMemcpyAsync(out + O_EMB, E, (size_t)4096 * 256 * sizeof(float),
                   hipMemcpyDeviceToDevice, stream);
}

// Round 4
// 418.678 us; speedup vs baseline: 7.4375x; 1.2491x over previous
//
#include <hip/hip_runtime.h>
#include <float.h>
#include <math.h>

typedef __attribute__((ext_vector_type(8))) short bf16x8;
typedef __attribute__((ext_vector_type(4))) float f32x4;

// d_out float offsets (loss, quantized, perplexity, embedding, indices, encodings)
#define O_Q    1
#define O_PERP 8388609
#define O_EMB  8388610
#define O_IDX  9437186
#define O_ENC  9469954

// workspace float offsets: ETpk limb-image at 0 (4 MB)
#define W_CB   1048576
#define W_CNT  1052672
#define W_BS   1056768

#define MARGIN 0.01f

__device__ __forceinline__ unsigned short bf16_rne(float x) {
    unsigned u = __float_as_uint(x);
    unsigned r = u + 0x7FFFu + ((u >> 16) & 1u);
    return (unsigned short)(r >> 16);
}

__device__ __forceinline__ void gld_lds16(const void* g, void* l) {
    __builtin_amdgcn_global_load_lds(
        (const __attribute__((address_space(1))) unsigned int*)g,
        (__attribute__((address_space(3))) unsigned int*)l, 16, 0, 0);
}

__device__ __forceinline__ unsigned long long u64min(unsigned long long a, unsigned long long b){ return a < b ? a : b; }
__device__ __forceinline__ unsigned long long u64max(unsigned long long a, unsigned long long b){ return a > b ? a : b; }

__device__ __forceinline__ unsigned long long packkey(float s, int k) {
    unsigned u = __float_as_uint(s);
    u = (u & 0x80000000u) ? ~u : (u | 0x80000000u);
    return ((unsigned long long)u << 32) | (unsigned)k;
}
__device__ __forceinline__ float unpackf(unsigned long long key) {
    unsigned u = (unsigned)(key >> 32);
    u = (u & 0x80000000u) ? (u & 0x7FFFFFFFu) : ~u;
    return __uint_as_float(u);
}

// ---- E -> limb image for global_load_lds staging.
// chunk(kt,ks) 32KB = [limb2][codefrag16][64 units x 16B], unit=(c*16+row)
__global__ __launch_bounds__(256)
void k_prep(const float* __restrict__ E, char* __restrict__ ETpk)
{
    int gid = blockIdx.x * 256 + threadIdx.x;   // 131072 = 4096 codes * 32 octets
    int code = gid >> 5, oct = gid & 31;
    const float* ep = E + (size_t)code * 256 + oct * 8;
    float4 a = *(const float4*)ep, c4 = *(const float4*)(ep + 4);
    float v[8] = {a.x, a.y, a.z, a.w, c4.x, c4.y, c4.z, c4.w};
    unsigned hw[8], lw[8];
#pragma unroll
    for (int i = 0; i < 8; ++i) {
        unsigned short h = bf16_rne(v[i]);
        float hf = __uint_as_float((unsigned)h << 16);
        hw[i] = h; lw[i] = bf16_rne(v[i] - hf);
    }
    uint4 vh = {hw[0]|(hw[1]<<16), hw[2]|(hw[3]<<16), hw[4]|(hw[5]<<16), hw[6]|(hw[7]<<16)};
    uint4 vl = {lw[0]|(lw[1]<<16), lw[2]|(lw[3]<<16), lw[4]|(lw[5]<<16), lw[6]|(lw[7]<<16)};
    int kt = code >> 8, cf = (code >> 4) & 15, row = code & 15;
    int dtv = oct >> 2, c = oct & 3;
    size_t chunk = (size_t)(kt * 8 + dtv) * 32768;
    *(uint4*)(ETpk + chunk + (size_t)((0*16 + cf) * 64 + (c*16 + row)) * 16) = vh;
    *(uint4*)(ETpk + chunk + (size_t)((1*16 + cf) * 64 + (c*16 + row)) * 16) = vl;
}

// ---- 0.5*||e_k||^2 (fp32)
__global__ __launch_bounds__(256)
void k_cbias(const float* __restrict__ E, float* __restrict__ cb)
{
    const int tid = threadIdx.x;
    const int k   = blockIdx.x * 16 + (tid >> 4);
    const int ch  = tid & 15;
    const float* p = E + (size_t)k * 256 + ch * 16;
    float s = 0.f;
#pragma unroll
    for (int i = 0; i < 4; ++i) {
        float4 v = *(const float4*)(p + i * 4);
        s += v.x*v.x + v.y*v.y + v.z*v.z + v.w*v.w;
    }
#pragma unroll
    for (int m = 1; m < 16; m <<= 1) s += __shfl_xor(s, m, 64);
    if (ch == 0) cb[k] = 0.5f * s;
}

// ---- main: limb-MFMA distances + top2 argmin + rescore + fused outputs
// grid 256, block 512 (8 waves 2Mx4N), tile 128 tok x 256 codes/kt, k32 steps
// A double-buffered [0,32K), B TRIPLE-buffered [32K,128K).
// Pipeline: counted vmcnt (never drain stores in-loop), stage B 2 rds ahead.
__global__ __launch_bounds__(512, 1)
void k_main(const float* __restrict__ X, const char* __restrict__ ETpk,
            const float* __restrict__ cbh, const float* __restrict__ E,
            float* __restrict__ out, int* __restrict__ counts,
            float* __restrict__ bscore)
{
    extern __shared__ char lds[];

    const int tid  = threadIdx.x;
    const int lane = tid & 63;
    const int wid  = tid >> 6;
    const int wm   = wid >> 2;      // 0..1 token half
    const int wn   = wid & 3;       // 0..3 code quarter
    const int n0   = blockIdx.x * 128;
    const int b    = n0 >> 10;
    const int l0   = n0 & 1023;
    const int tokA = tid & 127;     // A-staging unit: (token, d-octet)
    const int octA = tid >> 7;

    f32x4 acc[4][4];
#pragma unroll
    for (int mi = 0; mi < 4; ++mi)
#pragma unroll
        for (int nj = 0; nj < 4; ++nj) acc[mi][nj] = (f32x4){0.f,0.f,0.f,0.f};

    // per-slot top2: exact fp32 scores + packed code indices (i1 = low16, i2 = high16)
    float s1[16], s2[16];
    unsigned ipack[16];
#pragma unroll
    for (int s = 0; s < 16; ++s) { s1[s] = FLT_MAX; s2[s] = FLT_MAX; ipack[s] = 0; }

    const size_t xbase = (size_t)b * 262144 + l0;
    float* encB = out + (size_t)O_ENC + (size_t)n0 * 4096;   // base ≡ 2 mod 4 floats: float2 ops only

    auto stageB = [&](int rnd, int bufsel) {
        const char* src = ETpk + (size_t)rnd * 32768;
        char* dst = lds + 32768 + bufsel * 32768;
#pragma unroll
        for (int i = 0; i < 4; ++i)
            gld_lds16(src + i*8192 + tid*16, dst + i*8192 + tid*16);
    };
    auto loadA = [&](int rnd, float* xa) {
        const float* src = X + xbase + (size_t)((rnd & 7) * 32 + octA * 8) * 1024 + tokA;
#pragma unroll
        for (int i = 0; i < 8; ++i) xa[i] = src[(size_t)i * 1024];
    };
    auto writeA = [&](int bufsel, const float* xa) {
        unsigned hw[8], lw[8];
#pragma unroll
        for (int i = 0; i < 8; ++i) {
            unsigned short h16 = bf16_rne(xa[i]);
            float hf = __uint_as_float((unsigned)h16 << 16);
            hw[i] = h16; lw[i] = bf16_rne(xa[i] - hf);
        }
        uint4 vh = {hw[0]|(hw[1]<<16), hw[2]|(hw[3]<<16), hw[4]|(hw[5]<<16), hw[6]|(hw[7]<<16)};
        uint4 vl = {lw[0]|(lw[1]<<16), lw[2]|(lw[3]<<16), lw[4]|(lw[5]<<16), lw[6]|(lw[7]<<16)};
        char* dstc = lds + bufsel * 16384 + (tokA >> 4) * 1024 + (octA * 16 + (tokA & 15)) * 16;
        *(uint4*)dstc = vh;
        *(uint4*)(dstc + 8192) = vl;
    };

    // prologue: A(0) and B chunks 0,1 staged; full drain once
    {
        float xa[8];
        loadA(0, xa);
        stageB(0, 0);
        stageB(1, 1);
        writeA(0, xa);
    }
    __syncthreads();

#pragma unroll 1
    for (int rd = 0; rd < 128; ++rd) {
        const int asel = rd & 1;
        const char* A  = lds + asel * 16384;
        const char* Bp = lds + 32768 + (rd % 3) * 32768;
        float xa[8];
        // issue window: loadA FIRST (its reg-dep wait at writeA then guarantees
        // stageB(rd+1) done without draining stageB(rd+2)/stores)
        loadA(rd + 1 < 128 ? rd + 1 : 127, xa);
        stageB(rd + 2 < 128 ? rd + 2 : 127, (rd + 2) % 3);
        {   // zero-fill one token row of the one-hot block (4 float2/thread)
            float2 z2 = make_float2(0.f, 0.f);
            float* zb = encB + (size_t)rd * 4096;
#pragma unroll
            for (int i = 0; i < 4; ++i)
                *(float2*)(zb + i * 1024 + tid * 2) = z2;
        }

        // one k32-step, phased operands (as round 3)
        {
            bf16x8 ah[4], al[4], bt[4];
#pragma unroll
            for (int mi = 0; mi < 4; ++mi)
                ah[mi] = *(const bf16x8*)(A + (wm*4 + mi)*1024 + lane*16);
#pragma unroll
            for (int nj = 0; nj < 4; ++nj)
                bt[nj] = *(const bf16x8*)(Bp + (wn*4 + nj)*1024 + lane*16);
#pragma unroll
            for (int nj = 0; nj < 4; ++nj)
#pragma unroll
                for (int mi = 0; mi < 4; ++mi)
                    acc[mi][nj] = __builtin_amdgcn_mfma_f32_16x16x32_bf16(ah[mi], bt[nj], acc[mi][nj], 0, 0, 0);
#pragma unroll
            for (int mi = 0; mi < 4; ++mi)
                al[mi] = *(const bf16x8*)(A + 8192 + (wm*4 + mi)*1024 + lane*16);
#pragma unroll
            for (int nj = 0; nj < 4; ++nj)
#pragma unroll
                for (int mi = 0; mi < 4; ++mi)
                    acc[mi][nj] = __builtin_amdgcn_mfma_f32_16x16x32_bf16(al[mi], bt[nj], acc[mi][nj], 0, 0, 0);
#pragma unroll
            for (int nj = 0; nj < 4; ++nj)
                bt[nj] = *(const bf16x8*)(Bp + 16384 + (wn*4 + nj)*1024 + lane*16);
#pragma unroll
            for (int nj = 0; nj < 4; ++nj)
#pragma unroll
                for (int mi = 0; mi < 4; ++mi) {
                    acc[mi][nj] = __builtin_amdgcn_mfma_f32_16x16x32_bf16(ah[mi], bt[nj], acc[mi][nj], 0, 0, 0);
                    acc[mi][nj] = __builtin_amdgcn_mfma_f32_16x16x32_bf16(al[mi], bt[nj], acc[mi][nj], 0, 0, 0);
                }
        }

        if ((rd & 7) == 7) {
            const int kt = rd >> 3;
            const int cb0 = kt * 256 + wn * 64 + (lane & 15);
            float cbv[4];
#pragma unroll
            for (int nj = 0; nj < 4; ++nj) cbv[nj] = cbh[cb0 + nj * 16];
#pragma unroll
            for (int mi = 0; mi < 4; ++mi)
#pragma unroll
                for (int q = 0; q < 4; ++q) {
                    const int slot = mi * 4 + q;
#pragma unroll
                    for (int nj = 0; nj < 4; ++nj) {
                        float s = cbv[nj] - acc[mi][nj][q];
                        unsigned code = (unsigned)(cb0 + nj * 16);
                        if (s < s1[slot]) {
                            s2[slot] = s1[slot];
                            ipack[slot] = ((ipack[slot] & 0xFFFFu) << 16) | code;
                            s1[slot] = s;
                        } else if (s < s2[slot]) {
                            s2[slot] = s;
                            ipack[slot] = (ipack[slot] & 0xFFFFu) | (code << 16);
                        }
                        acc[mi][nj][q] = 0.f;
                    }
                }
        }

        writeA((rd + 1) & 1, xa);
        // counted waits: stage loads for rd+1 are guaranteed (all older than the
        // ~8 newest ops); stores + stageB(rd+2) stay in flight across the barrier
        asm volatile("s_waitcnt vmcnt(8)" ::: "memory");
        asm volatile("s_waitcnt lgkmcnt(0)" ::: "memory");
        __builtin_amdgcn_s_barrier();
    }

    __syncthreads();   // full drain: store-acks (zero->one-hot ordering) + LDS reuse

    // pack keys and butterfly-merge top2 across the 16 code-lanes
    unsigned long long key1[16], key2[16];
#pragma unroll
    for (int s = 0; s < 16; ++s) {
        key1[s] = packkey(s1[s], (int)(ipack[s] & 0xFFFFu));
        key2[s] = packkey(s2[s], (int)(ipack[s] >> 16));
    }
#pragma unroll
    for (int m = 1; m < 16; m <<= 1) {
#pragma unroll
        for (int s = 0; s < 16; ++s) {
            unsigned long long o1 = __shfl_xor(key1[s], m, 64);
            unsigned long long o2 = __shfl_xor(key2[s], m, 64);
            unsigned long long lo = u64min(key1[s], o1);
            unsigned long long hi = u64min(u64max(key1[s], o1), u64min(key2[s], o2));
            key1[s] = lo; key2[s] = hi;
        }
    }

    unsigned long long* scr = (unsigned long long*)lds;       // 128*4*2 u64 = 8 KB
    int* ids = (int*)(lds + 16384);                           // 128 ints
    float* wp = (float*)(lds + 16384 + 512);                  // 8 floats
    if ((lane & 15) == 0) {
#pragma unroll
        for (int mi = 0; mi < 4; ++mi)
#pragma unroll
            for (int q = 0; q < 4; ++q) {
                int slot = mi * 4 + q;
                int tl = wm * 64 + mi * 16 + ((lane >> 4) << 2) + q;
                scr[(tl * 4 + wn) * 2    ] = key1[slot];
                scr[(tl * 4 + wn) * 2 + 1] = key2[slot];
            }
    }
    __syncthreads();

    if (tid < 128) {
        unsigned long long a1 = scr[tid * 8], a2 = scr[tid * 8 + 1];
#pragma unroll
        for (int w = 1; w < 4; ++w) {
            unsigned long long b1 = scr[(tid * 4 + w) * 2];
            unsigned long long b2 = scr[(tid * 4 + w) * 2 + 1];
            unsigned long long lo = u64min(a1, b1);
            unsigned long long hi = u64min(u64max(a1, b1), u64min(a2, b2));
            a1 = lo; a2 = hi;
        }
        int k = (int)(a1 & 0xFFFFFFFFull);
        float g1 = unpackf(a1), g2 = unpackf(a2);
        if (g2 - g1 <= MARGIN) {
            int ka = k, kb = (int)(a2 & 0xFFFFFFFFull);
            float d1 = 0.f, d2 = 0.f;
            for (int d = 0; d < 256; d += 2) {
                float xv0 = X[xbase + (size_t)d * 1024 + tid];
                float xv1 = X[xbase + (size_t)(d + 1) * 1024 + tid];
                float e10 = E[(size_t)ka * 256 + d], e11 = E[(size_t)ka * 256 + d + 1];
                float e20 = E[(size_t)kb * 256 + d], e21 = E[(size_t)kb * 256 + d + 1];
                float f10 = xv0 - e10, f11 = xv1 - e11;
                float f20 = xv0 - e20, f21 = xv1 - e21;
                d1 += f10 * f10 + f11 * f11;
                d2 += f20 * f20 + f21 * f21;
            }
            if (d2 < d1 || (d2 == d1 && kb < ka)) k = kb;
        }
        ids[tid] = k;
        out[(size_t)O_IDX + n0 + tid] = (float)k;
        atomicAdd(&counts[k], 1);
        out[(size_t)O_ENC + (size_t)(n0 + tid) * 4096 + k] = 1.0f;
    }
    __syncthreads();

    // fused quantize (STE arithmetic) + exact fp32 loss partial
    float dl = 0.f;
#pragma unroll 4
    for (int r = 0; r < 64; ++r) {
        int lin = r * 512 + tid;
        int d = lin >> 7, t = lin & 127;
        float q  = E[(size_t)ids[t] * 256 + d];
        float xv = X[xbase + (size_t)d * 1024 + t];
        out[(size_t)O_Q + xbase + (size_t)d * 1024 + t] = xv + (q - xv);
        float df = q - xv;
        dl += df * df;
    }
#pragma unroll
    for (int m = 1; m < 64; m <<= 1) dl += __shfl_xor(dl, m, 64);
    if (lane == 0) wp[wid] = dl;
    __syncthreads();
    if (tid == 0) {
        float s = 0.f;
#pragma unroll
        for (int w = 0; w < 8; ++w) s += wp[w];
        bscore[blockIdx.x] = s;
    }
}

// ---- scalars: loss + perplexity
__global__ __launch_bounds__(256)
void k_final(const float* __restrict__ bscore, const int* __restrict__ counts,
             float* __restrict__ out)
{
    const int tid = threadIdx.x;
    float s = bscore[tid];
    float h = 0.f;
#pragma unroll
    for (int i = 0; i < 16; ++i) {
        float p = (float)counts[tid * 16 + i] * (1.0f / 32768.f);
        h += p * logf(p + 1e-10f);
    }
#pragma unroll
    for (int m = 1; m < 64; m <<= 1) {
        s += __shfl_xor(s, m, 64);
        h += __shfl_xor(h, m, 64);
    }
    __shared__ float rs[4], rh[4];
    if ((tid & 63) == 0) { rs[tid >> 6] = s; rh[tid >> 6] = h; }
    __syncthreads();
    if (tid == 0) {
        float S = rs[0] + rs[1] + rs[2] + rs[3];
        float H = rh[0] + rh[1] + rh[2] + rh[3];
        out[0]      = 0.25f * S / 8388608.f;
        out[O_PERP] = expf(-H);
    }
}

extern "C" void kernel_launch(void* const* d_in, const int* in_sizes, int n_in,
                              void* d_out, int out_size, void* d_ws, size_t ws_size,
                              hipStream_t stream)
{
    (void)in_sizes; (void)n_in; (void)out_size; (void)ws_size;
    const float* X = (const float*)d_in[0];
    const float* E = (const float*)d_in[1];
    float* out = (float*)d_out;
    float* ws  = (float*)d_ws;
    char*  ETpk   = (char*)ws;
    float* cbh    = ws + W_CB;
    int*   counts = (int*)(ws + W_CNT);
    float* bsc    = ws + W_BS;

    hipMemsetAsync(counts, 0, 4096 * sizeof(int), stream);
    k_prep <<<512, 256, 0, stream>>>(E, ETpk);
    k_cbias<<<256, 256, 0, stream>>>(E, cbh);
    hipFuncSetAttribute((const void*)k_main, hipFuncAttributeMaxDynamicSharedMemorySize, 131072);
    k_main <<<256, 512, 131072, stream>>>(X, ETpk, cbh, E, out, counts, bsc);
    k_final<<<1, 256, 0, stream>>>(bsc, counts, out);
    hipMemcpyAsync(out + O_EMB, E, (size_t)4096 * 256 * sizeof(float),
                   hipMemcpyDeviceToDevice, stream);
}